// Round 4
// baseline (202.720 us; speedup 1.0000x reference)
//
#include <hip/hip_runtime.h>
#include <hip/hip_bf16.h>

typedef unsigned int uint32;
typedef unsigned short ushort;
typedef __attribute__((ext_vector_type(4))) float floatx4;
typedef __attribute__((ext_vector_type(8))) __bf16 bf16x8;

#define NPTS 8192

// ---------------- bf16 helpers (RNE) ----------------
__device__ __forceinline__ ushort f2bf(float f) {
    uint32 u = __float_as_uint(f);
    uint32 r = (u + 0x7fffu + ((u >> 16) & 1u)) >> 16;
    return (ushort)r;
}
__device__ __forceinline__ float bf1(ushort u) { return __uint_as_float((uint32)u << 16); }
__device__ __forceinline__ float bflo(uint32 u) { return __uint_as_float(u << 16); }
__device__ __forceinline__ float bfhi(uint32 u) { return __uint_as_float(u & 0xffff0000u); }

// ---------------- cast x -> bf16 ----------------
__global__ __launch_bounds__(256) void cast_x_kernel(const float* __restrict__ x,
                                                     ushort* __restrict__ xb) {
    int i = (blockIdx.x * 256 + threadIdx.x) * 4;
    float4 v = *(const float4*)(x + i);
    ushort4 o;
    o.x = f2bf(v.x); o.y = f2bf(v.y); o.z = f2bf(v.z); o.w = f2bf(v.w);
    *(ushort4*)(xb + i) = o;
}

// ---------------- pack transposed bf16 weights + fused qkv bias ----------------
__global__ __launch_bounds__(256) void pack_w_kernel(const float* __restrict__ Wq, const float* __restrict__ Wk,
                                                     const float* __restrict__ Wv, const float* __restrict__ Wo,
                                                     const float* __restrict__ bq, const float* __restrict__ bk,
                                                     const float* __restrict__ bv,
                                                     ushort* __restrict__ Wqkvt, ushort* __restrict__ Wot,
                                                     float* __restrict__ biasqkv) {
    int f = blockIdx.x * 256 + threadIdx.x;  // 0 .. 262143
    if (f < 768 * 256) {
        int n = f >> 8, k = f & 255;
        int seg = n >> 8, nc = n & 255;
        const float* W = (seg == 0) ? Wq : (seg == 1) ? Wk : Wv;
        Wqkvt[f] = f2bf(W[k * 256 + nc]);
    } else {
        int g = f - 768 * 256;
        int n = g >> 8, k = g & 255;
        Wot[g] = f2bf(Wo[k * 256 + n]);
    }
    if (f < 768) biasqkv[f] = (f < 256) ? bq[f] : (f < 512) ? bk[f - 256] : bv[f - 512];
}

// ---------------- MFMA bf16 GEMM: out[M,N] = A[M,256] @ Wt^T + bias ----------------
template <bool OUT_BF16>
__global__ __launch_bounds__(256) void gemm_mfma(const ushort* __restrict__ A,
                                                 const ushort* __restrict__ Wt,
                                                 const float* __restrict__ bias,
                                                 void* __restrict__ outv, int N) {
    __shared__ __align__(16) ushort As[128 * 32];  // [m][k] rows of 64B
    __shared__ __align__(16) ushort Bs[128 * 32];  // [n][k]
    const int tid = threadIdx.x;
    const int w = tid >> 6, lane = tid & 63;
    const int m0 = blockIdx.y * 128, n0 = blockIdx.x * 128;
    const int wm = (w & 1) * 64, wn = (w >> 1) * 64;

    const int lrow = lane >> 2;
    const int lcol = (lane & 3) * 16;

    floatx4 acc[4][4] = {};

    for (int kt = 0; kt < 256; kt += 32) {
        __syncthreads();
#pragma unroll
        for (int t = 0; t < 2; ++t) {
            const int r = (w * 2 + t) * 16 + lrow;
            const char* ga = (const char*)(A + (size_t)(m0 + r) * 256 + kt) + lcol;
            const char* gb = (const char*)(Wt + (size_t)(n0 + r) * 256 + kt) + lcol;
            __builtin_amdgcn_global_load_lds((const __attribute__((address_space(1))) void*)ga,
                                             (__attribute__((address_space(3))) void*)((char*)As + (w * 2 + t) * 1024),
                                             16, 0, 0);
            __builtin_amdgcn_global_load_lds((const __attribute__((address_space(1))) void*)gb,
                                             (__attribute__((address_space(3))) void*)((char*)Bs + (w * 2 + t) * 1024),
                                             16, 0, 0);
        }
        __syncthreads();

        bf16x8 af[4], bg[4];
#pragma unroll
        for (int i = 0; i < 4; ++i) {
            af[i] = *(const bf16x8*)&As[(wm + i * 16 + (lane & 15)) * 32 + (lane >> 4) * 8];
            bg[i] = *(const bf16x8*)&Bs[(wn + i * 16 + (lane & 15)) * 32 + (lane >> 4) * 8];
        }
#pragma unroll
        for (int mi = 0; mi < 4; ++mi)
#pragma unroll
            for (int ni = 0; ni < 4; ++ni)
                acc[mi][ni] = __builtin_amdgcn_mfma_f32_16x16x32_bf16(af[mi], bg[ni], acc[mi][ni], 0, 0, 0);
    }

#pragma unroll
    for (int ni = 0; ni < 4; ++ni) {
        const int col = n0 + wn + ni * 16 + (lane & 15);
        const float bv = bias[col];
#pragma unroll
        for (int mi = 0; mi < 4; ++mi) {
            const int row0 = m0 + wm + mi * 16 + (lane >> 4) * 4;
#pragma unroll
            for (int r = 0; r < 4; ++r) {
                const float v = acc[mi][ni][r] + bv;
                if (OUT_BF16)
                    ((ushort*)outv)[(size_t)(row0 + r) * N + col] = f2bf(v);
                else
                    ((float*)outv)[(size_t)(row0 + r) * N + col] = v;
            }
        }
    }
}

// ---------------- bias MLP precompute: bias_g[p][h][j] (bf16) ----------------
__global__ __launch_bounds__(256) void bias_mlp_kernel(
    const float* __restrict__ xyz, const int* __restrict__ idx,
    const float* __restrict__ W1, const float* __restrict__ b1,
    const float* __restrict__ W2, const float* __restrict__ b2,
    ushort* __restrict__ bias_g) {
    __shared__ float W1s[96], b1s[32], W2s[256], b2s[8];
    const int tid = threadIdx.x, wid = tid >> 6, lane = tid & 63;
    if (tid < 96) W1s[tid] = W1[tid];
    if (tid < 32) b1s[tid] = b1[tid];
    W2s[tid] = W2[tid];
    if (tid < 8) b2s[tid] = b2[tid];
    __syncthreads();
    const int p = blockIdx.x * 4 + wid;
    const int b = p >> 13, n = p & 8191;
    if (lane < 32) {
        const int j = lane;
        const int nj = idx[(size_t)p * 32 + j];
        const size_t pb = ((size_t)b * NPTS + n) * 3;
        const size_t nb = ((size_t)b * NPTS + nj) * 3;
        const float rx = xyz[pb + 0] - xyz[nb + 0];
        const float ry = xyz[pb + 1] - xyz[nb + 1];
        const float rz = xyz[pb + 2] - xyz[nb + 2];
        float acc[8];
#pragma unroll
        for (int h = 0; h < 8; ++h) acc[h] = b2s[h];
#pragma unroll
        for (int u = 0; u < 32; ++u) {
            float hv = rx * W1s[u] + ry * W1s[32 + u] + rz * W1s[64 + u] + b1s[u];
            hv = fmaxf(hv, 0.f);
#pragma unroll
            for (int h = 0; h < 8; ++h) acc[h] += hv * W2s[u * 8 + h];
        }
#pragma unroll
        for (int h = 0; h < 8; ++h) bias_g[((size_t)p * 8 + h) * 32 + j] = f2bf(acc[h]);
    }
}

// ---------------- attention: head-sliced for per-XCD L2 residency ----------------
// head = blockIdx & 7 (round-robin block->XCD => each XCD gathers one head's
// K/V slice = 2 MB, fits 4 MB L2). Wave handles 2 (point,head) units.
__global__ __launch_bounds__(256) void attn_kernel(
    const ushort* __restrict__ qkv, const int* __restrict__ idx,
    const ushort* __restrict__ bias_g, ushort* __restrict__ out) {
    __shared__ __align__(16) float q_s[4][2][32];
    __shared__ float attn_s[4][2][32];
    __shared__ int idx_s[4][2][32];

    const int tid = threadIdx.x, wid = tid >> 6, lane = tid & 63;
    const int h = blockIdx.x & 7;
    const int pg = blockIdx.x >> 3;
    const int pbase = pg * 8 + wid * 2;

    // stage idx + q (lane = s*32 + t)
    {
        const int s = lane >> 5, t = lane & 31;
        const int p = pbase + s;
        idx_s[wid][s][t] = idx[(size_t)p * 32 + t];
        q_s[wid][s][t] = bf1(qkv[(size_t)p * 768 + h * 32 + t]);
    }
    __syncthreads();

    // scores + softmax: lane = (s = point, j = neighbor)
    {
        const int s = lane >> 5, j = lane & 31;
        const int p = pbase + s;
        const int b = p >> 13;
        const int nj = idx_s[wid][s][j];
        const uint4* kp = (const uint4*)(qkv + ((size_t)b * NPTS + nj) * 768 + 256 + h * 32);
        float d = 0.f;
#pragma unroll
        for (int c = 0; c < 4; ++c) {
            uint4 kv = kp[c];
            float4 qa = *(const float4*)&q_s[wid][s][c * 8];
            float4 qb = *(const float4*)&q_s[wid][s][c * 8 + 4];
            d += bflo(kv.x) * qa.x + bfhi(kv.x) * qa.y
               + bflo(kv.y) * qa.z + bfhi(kv.y) * qa.w
               + bflo(kv.z) * qb.x + bfhi(kv.z) * qb.y
               + bflo(kv.w) * qb.z + bfhi(kv.w) * qb.w;
        }
        float sc = d * 0.17677669529663687f + bf1(bias_g[((size_t)p * 8 + h) * 32 + j]);
        float m = sc;
#pragma unroll
        for (int msk = 16; msk >= 1; msk >>= 1) m = fmaxf(m, __shfl_xor(m, msk, 64));
        float e = __expf(sc - m);
        float ssum = e;
#pragma unroll
        for (int msk = 16; msk >= 1; msk >>= 1) ssum += __shfl_xor(ssum, msk, 64);
        attn_s[wid][s][j] = e / ssum;
    }
    __syncthreads();

    // PV: lane = (s2 = point, hj = neighbor-half, d2 = dim-pair)
    {
        const int s2 = lane >> 5, hj = (lane >> 4) & 1, d2 = lane & 15;
        const int p2 = pbase + s2;
        const int b2 = p2 >> 13;
        float ax = 0.f, ay = 0.f;
#pragma unroll
        for (int jj = 0; jj < 16; ++jj) {
            const int j2 = hj * 16 + jj;
            const int nj = idx_s[wid][s2][j2];
            const float w = attn_s[wid][s2][j2];
            const uint32 v = *(const uint32*)(qkv + ((size_t)b2 * NPTS + nj) * 768 + 512 + h * 32 + d2 * 2);
            ax += w * bflo(v);
            ay += w * bfhi(v);
        }
        ax += __shfl_xor(ax, 16, 64);
        ay += __shfl_xor(ay, 16, 64);
        if (hj == 0) {
            const uint32 o = (uint32)f2bf(ax) | ((uint32)f2bf(ay) << 16);
            *(uint32*)(out + (size_t)p2 * 256 + h * 32 + d2 * 2) = o;
        }
    }
}

// ---------------- launch ----------------
extern "C" void kernel_launch(void* const* d_in, const int* in_sizes, int n_in,
                              void* d_out, int out_size, void* d_ws, size_t ws_size,
                              hipStream_t stream) {
    const float* x   = (const float*)d_in[0];
    const float* xyz = (const float*)d_in[1];
    const int*   idx = (const int*)d_in[2];
    const float* Wq = (const float*)d_in[3];
    const float* bq = (const float*)d_in[4];
    const float* Wk = (const float*)d_in[5];
    const float* bk = (const float*)d_in[6];
    const float* Wv = (const float*)d_in[7];
    const float* bv = (const float*)d_in[8];
    const float* Wo = (const float*)d_in[9];
    const float* bo = (const float*)d_in[10];
    const float* W1 = (const float*)d_in[11];
    const float* b1 = (const float*)d_in[12];
    const float* W2 = (const float*)d_in[13];
    const float* b2 = (const float*)d_in[14];

    const int M = 16384;  // B*N
    char* wsb = (char*)d_ws;
    ushort* x_bf    = (ushort*)wsb;                   // 8 MB (aliased by aout_bf)
    ushort* aout_bf = x_bf;                           // x consumed by gemm_qkv before attn writes
    ushort* qkv_bf  = (ushort*)(wsb + 8388608);       // 25.17 MB
    ushort* Wqkvt   = (ushort*)(wsb + 33554432);      // 384 KB
    ushort* Wot     = (ushort*)(wsb + 33947648);      // 128 KB
    float*  biasqkv = (float*)(wsb + 34078720);       // 3 KB
    ushort* bias_g  = (ushort*)(wsb + 34081792);      // 8 MB
    // total ~42.5 MB

    cast_x_kernel<<<(M * 256 / 4) / 256, 256, 0, stream>>>(x, x_bf);
    pack_w_kernel<<<(768 * 256 + 256 * 256) / 256, 256, 0, stream>>>(
        Wq, Wk, Wv, Wo, bq, bk, bv, Wqkvt, Wot, biasqkv);

    gemm_mfma<true><<<dim3(6, 128), 256, 0, stream>>>(x_bf, Wqkvt, biasqkv, qkv_bf, 768);

    bias_mlp_kernel<<<M / 4, 256, 0, stream>>>(xyz, idx, W1, b1, W2, b2, bias_g);

    attn_kernel<<<M, 256, 0, stream>>>(qkv_bf, idx, bias_g, aout_bf);

    gemm_mfma<false><<<dim3(2, 128), 256, 0, stream>>>(aout_bf, Wot, bo, d_out, 256);
}

// Round 5
// 198.706 us; speedup vs baseline: 1.0202x; 1.0202x over previous
//
#include <hip/hip_runtime.h>
#include <hip/hip_bf16.h>

typedef unsigned int uint32;
typedef unsigned short ushort;
typedef __attribute__((ext_vector_type(4))) float floatx4;
typedef __attribute__((ext_vector_type(8))) __bf16 bf16x8;

#define NPTS 8192

// ---------------- bf16 helpers (RNE) ----------------
__device__ __forceinline__ ushort f2bf(float f) {
    uint32 u = __float_as_uint(f);
    uint32 r = (u + 0x7fffu + ((u >> 16) & 1u)) >> 16;
    return (ushort)r;
}
__device__ __forceinline__ float bf1(ushort u) { return __uint_as_float((uint32)u << 16); }
__device__ __forceinline__ float bflo(uint32 u) { return __uint_as_float(u << 16); }
__device__ __forceinline__ float bfhi(uint32 u) { return __uint_as_float(u & 0xffff0000u); }

// ---------------- prep: cast x -> bf16 | pack weights | bias-MLP precompute ----------------
// grid: [0,4096) cast, [4096,5120) pack, [5120,7168) bias MLP (block-uniform branches)
__global__ __launch_bounds__(256) void prep_kernel(
    const float* __restrict__ x, const float* __restrict__ xyz, const int* __restrict__ idx,
    const float* __restrict__ Wq, const float* __restrict__ Wk,
    const float* __restrict__ Wv, const float* __restrict__ Wo,
    const float* __restrict__ bq, const float* __restrict__ bk, const float* __restrict__ bv,
    const float* __restrict__ W1, const float* __restrict__ b1,
    const float* __restrict__ W2, const float* __restrict__ b2,
    ushort* __restrict__ xb, ushort* __restrict__ Wqkvt, ushort* __restrict__ Wot,
    float* __restrict__ biasqkv, ushort* __restrict__ bias_g) {
    const int bi = blockIdx.x;
    const int tid = threadIdx.x;
    if (bi < 4096) {
        // cast x (16384*256 fp32 -> bf16), float4 per thread
        int i = (bi * 256 + tid) * 4;
        float4 v = *(const float4*)(x + i);
        ushort4 o;
        o.x = f2bf(v.x); o.y = f2bf(v.y); o.z = f2bf(v.z); o.w = f2bf(v.w);
        *(ushort4*)(xb + i) = o;
    } else if (bi < 5120) {
        // pack transposed weights
        int f = (bi - 4096) * 256 + tid;  // 0 .. 262143
        if (f < 768 * 256) {
            int n = f >> 8, k = f & 255;
            int seg = n >> 8, nc = n & 255;
            const float* W = (seg == 0) ? Wq : (seg == 1) ? Wk : Wv;
            Wqkvt[f] = f2bf(W[k * 256 + nc]);
        } else {
            int g = f - 768 * 256;
            int n = g >> 8, k = g & 255;
            Wot[g] = f2bf(Wo[k * 256 + n]);
        }
        if (f < 768) biasqkv[f] = (f < 256) ? bq[f] : (f < 512) ? bk[f - 256] : bv[f - 512];
    } else {
        // bias MLP: 8 points per block, 2 per wave (all 64 lanes active)
        __shared__ float W1s[96], b1s[32], W2s[256], b2s[8];
        if (tid < 96) W1s[tid] = W1[tid];
        if (tid < 32) b1s[tid] = b1[tid];
        W2s[tid] = W2[tid];
        if (tid < 8) b2s[tid] = b2[tid];
        __syncthreads();
        const int wid = tid >> 6, lane = tid & 63;
        const int s = lane >> 5, j = lane & 31;
        const int p = (bi - 5120) * 8 + wid * 2 + s;
        const int b = p >> 13, n = p & 8191;
        const int nj = idx[(size_t)p * 32 + j];
        const size_t pb = ((size_t)b * NPTS + n) * 3;
        const size_t nb = ((size_t)b * NPTS + nj) * 3;
        const float rx = xyz[pb + 0] - xyz[nb + 0];
        const float ry = xyz[pb + 1] - xyz[nb + 1];
        const float rz = xyz[pb + 2] - xyz[nb + 2];
        float acc[8];
#pragma unroll
        for (int h = 0; h < 8; ++h) acc[h] = b2s[h];
#pragma unroll
        for (int u = 0; u < 32; ++u) {
            float hv = rx * W1s[u] + ry * W1s[32 + u] + rz * W1s[64 + u] + b1s[u];
            hv = fmaxf(hv, 0.f);
#pragma unroll
            for (int h = 0; h < 8; ++h) acc[h] += hv * W2s[u * 8 + h];
        }
#pragma unroll
        for (int h = 0; h < 8; ++h) bias_g[((size_t)p * 8 + h) * 32 + j] = f2bf(acc[h]);
    }
}

// ---------------- MFMA bf16 GEMM, 64x64 tile: out[M,N] = A[M,256] @ Wt^T + bias ----------------
// 4 waves; wave w computes 16-row M-strip (w*16) x 64 N. BK=32, K=256 -> 8 iters.
// High block count for latency hiding on this K-short GEMM.
template <bool OUT_BF16>
__global__ __launch_bounds__(256) void gemm_mfma64(const ushort* __restrict__ A,
                                                   const ushort* __restrict__ Wt,
                                                   const float* __restrict__ bias,
                                                   void* __restrict__ outv, int N) {
    __shared__ __align__(16) ushort As[64 * 32];  // [m][k] rows of 64B
    __shared__ __align__(16) ushort Bs[64 * 32];  // [n][k]
    const int tid = threadIdx.x;
    const int w = tid >> 6, lane = tid & 63;
    const int m0 = blockIdx.y * 64, n0 = blockIdx.x * 64;

    const int row = tid >> 2;          // 0..63 staging row
    const int col16 = (tid & 3) * 16;  // byte offset within 64B row

    floatx4 acc[4] = {};

    for (int kt = 0; kt < 256; kt += 32) {
        __syncthreads();
        {
            const char* ga = (const char*)(A + (size_t)(m0 + row) * 256 + kt) + col16;
            const char* gb = (const char*)(Wt + (size_t)(n0 + row) * 256 + kt) + col16;
            __builtin_amdgcn_global_load_lds((const __attribute__((address_space(1))) void*)ga,
                                             (__attribute__((address_space(3))) void*)((char*)As + w * 1024),
                                             16, 0, 0);
            __builtin_amdgcn_global_load_lds((const __attribute__((address_space(1))) void*)gb,
                                             (__attribute__((address_space(3))) void*)((char*)Bs + w * 1024),
                                             16, 0, 0);
        }
        __syncthreads();

        bf16x8 af = *(const bf16x8*)&As[(w * 16 + (lane & 15)) * 32 + (lane >> 4) * 8];
        bf16x8 bg[4];
#pragma unroll
        for (int ni = 0; ni < 4; ++ni)
            bg[ni] = *(const bf16x8*)&Bs[(ni * 16 + (lane & 15)) * 32 + (lane >> 4) * 8];
#pragma unroll
        for (int ni = 0; ni < 4; ++ni)
            acc[ni] = __builtin_amdgcn_mfma_f32_16x16x32_bf16(af, bg[ni], acc[ni], 0, 0, 0);
    }

    // epilogue: D[row=(lane>>4)*4+r][col=lane&15]
#pragma unroll
    for (int ni = 0; ni < 4; ++ni) {
        const int col = n0 + ni * 16 + (lane & 15);
        const float bv = bias[col];
        const int row0 = m0 + w * 16 + (lane >> 4) * 4;
#pragma unroll
        for (int r = 0; r < 4; ++r) {
            const float v = acc[ni][r] + bv;
            if (OUT_BF16)
                ((ushort*)outv)[(size_t)(row0 + r) * N + col] = f2bf(v);
            else
                ((float*)outv)[(size_t)(row0 + r) * N + col] = v;
        }
    }
}

// ---------------- attention: head-sliced (per-XCD L2 residency), no-max softmax ----------------
__global__ __launch_bounds__(256) void attn_kernel(
    const ushort* __restrict__ qkv, const int* __restrict__ idx,
    const ushort* __restrict__ bias_g, ushort* __restrict__ out) {
    __shared__ __align__(16) float q_s[4][2][32];
    __shared__ float e_s[4][2][32];
    __shared__ uint32 off_s[4][2][32];  // neighbor-row byte offsets
    __shared__ float ssum_s[4][2];

    const int tid = threadIdx.x, wid = tid >> 6, lane = tid & 63;
    const int h = blockIdx.x & 7;       // head -> XCD round-robin
    const int pg = blockIdx.x >> 3;
    const int pbase = pg * 8 + wid * 2;
    const char* base = (const char*)qkv;

    const int s = lane >> 5, j = lane & 31;
    const int p = pbase + s;
    const int b = p >> 13;

    // stage: byte offsets of neighbor rows (row pitch 768*2 = 1536 B) + q (fp32)
    off_s[wid][s][j] = (uint32)(idx[(size_t)p * 32 + j] + b * NPTS) * 1536u;
    q_s[wid][s][j] = bf1(qkv[(size_t)p * 768 + h * 32 + j]);
    __syncthreads();

    // scores + exp + sum (no max-pass; scores are O(1), exp can't overflow fp32)
    {
        const uint4* kp = (const uint4*)(base + off_s[wid][s][j] + 512 + h * 64);
        float d = 0.f;
#pragma unroll
        for (int c = 0; c < 4; ++c) {
            uint4 kv = kp[c];
            float4 qa = *(const float4*)&q_s[wid][s][c * 8];
            float4 qb = *(const float4*)&q_s[wid][s][c * 8 + 4];
            d += bflo(kv.x) * qa.x + bfhi(kv.x) * qa.y
               + bflo(kv.y) * qa.z + bfhi(kv.y) * qa.w
               + bflo(kv.z) * qb.x + bfhi(kv.z) * qb.y
               + bflo(kv.w) * qb.z + bfhi(kv.w) * qb.w;
        }
        const float sc = d * 0.17677669529663687f + bf1(bias_g[((size_t)p * 8 + h) * 32 + j]);
        const float e = __expf(sc);
        float ssum = e;
#pragma unroll
        for (int msk = 16; msk >= 1; msk >>= 1) ssum += __shfl_xor(ssum, msk, 64);
        e_s[wid][s][j] = e;
        if (j == 0) ssum_s[wid][s] = ssum;
    }
    __syncthreads();

    // PV: lane = (s2 = point, hj = neighbor-half, d2 = dim-pair); normalize at the end
    {
        const int s2 = lane >> 5, hj = (lane >> 4) & 1, d2 = lane & 15;
        const int p2 = pbase + s2;
        const float rinv = __builtin_amdgcn_rcpf(ssum_s[wid][s2]);
        float ax = 0.f, ay = 0.f;
#pragma unroll
        for (int jj = 0; jj < 16; ++jj) {
            const int j2 = hj * 16 + jj;
            const float wgt = e_s[wid][s2][j2];
            const uint32 v = *(const uint32*)(base + off_s[wid][s2][j2] + 1024 + h * 64 + d2 * 4);
            ax += wgt * bflo(v);
            ay += wgt * bfhi(v);
        }
        ax += __shfl_xor(ax, 16, 64);
        ay += __shfl_xor(ay, 16, 64);
        if (hj == 0) {
            const uint32 o = (uint32)f2bf(ax * rinv) | ((uint32)f2bf(ay * rinv) << 16);
            *(uint32*)(out + (size_t)p2 * 256 + h * 32 + d2 * 2) = o;
        }
    }
}

// ---------------- launch ----------------
extern "C" void kernel_launch(void* const* d_in, const int* in_sizes, int n_in,
                              void* d_out, int out_size, void* d_ws, size_t ws_size,
                              hipStream_t stream) {
    const float* x   = (const float*)d_in[0];
    const float* xyz = (const float*)d_in[1];
    const int*   idx = (const int*)d_in[2];
    const float* Wq = (const float*)d_in[3];
    const float* bq = (const float*)d_in[4];
    const float* Wk = (const float*)d_in[5];
    const float* bk = (const float*)d_in[6];
    const float* Wv = (const float*)d_in[7];
    const float* bv = (const float*)d_in[8];
    const float* Wo = (const float*)d_in[9];
    const float* bo = (const float*)d_in[10];
    const float* W1 = (const float*)d_in[11];
    const float* b1 = (const float*)d_in[12];
    const float* W2 = (const float*)d_in[13];
    const float* b2 = (const float*)d_in[14];

    char* wsb = (char*)d_ws;
    ushort* x_bf    = (ushort*)wsb;                   // 8 MB (aliased by aout_bf)
    ushort* aout_bf = x_bf;                           // x consumed by gemm_qkv before attn writes
    ushort* qkv_bf  = (ushort*)(wsb + 8388608);       // 25.17 MB
    ushort* Wqkvt   = (ushort*)(wsb + 33554432);      // 384 KB
    ushort* Wot     = (ushort*)(wsb + 33947648);      // 128 KB
    float*  biasqkv = (float*)(wsb + 34078720);       // 3 KB
    ushort* bias_g  = (ushort*)(wsb + 34081792);      // 8 MB

    prep_kernel<<<7168, 256, 0, stream>>>(x, xyz, idx, Wq, Wk, Wv, Wo, bq, bk, bv,
                                          W1, b1, W2, b2, x_bf, Wqkvt, Wot, biasqkv, bias_g);

    gemm_mfma64<true><<<dim3(12, 256), 256, 0, stream>>>(x_bf, Wqkvt, biasqkv, qkv_bf, 768);

    attn_kernel<<<16384, 256, 0, stream>>>(qkv_bf, idx, bias_g, aout_bf);

    gemm_mfma64<false><<<dim3(4, 256), 256, 0, stream>>>(aout_bf, Wot, bo, d_out, 256);
}

// Round 6
// 198.444 us; speedup vs baseline: 1.0215x; 1.0013x over previous
//
#include <hip/hip_runtime.h>
#include <hip/hip_bf16.h>

typedef unsigned int uint32;
typedef unsigned short ushort;
typedef __attribute__((ext_vector_type(4))) float floatx4;
typedef __attribute__((ext_vector_type(8))) __bf16 bf16x8;

#define NPTS 8192

// ---------------- bf16 helpers (RNE) ----------------
__device__ __forceinline__ ushort f2bf(float f) {
    uint32 u = __float_as_uint(f);
    uint32 r = (u + 0x7fffu + ((u >> 16) & 1u)) >> 16;
    return (ushort)r;
}
__device__ __forceinline__ float bf1(ushort u) { return __uint_as_float((uint32)u << 16); }
__device__ __forceinline__ float bflo(uint32 u) { return __uint_as_float(u << 16); }
__device__ __forceinline__ float bfhi(uint32 u) { return __uint_as_float(u & 0xffff0000u); }

// ---------------- prep: cast x -> bf16 | pack weights | bias-MLP precompute ----------------
// grid: [0,4096) cast, [4096,5120) pack, [5120,7168) bias MLP (block-uniform branches)
__global__ __launch_bounds__(256) void prep_kernel(
    const float* __restrict__ x, const float* __restrict__ xyz, const int* __restrict__ idx,
    const float* __restrict__ Wq, const float* __restrict__ Wk,
    const float* __restrict__ Wv, const float* __restrict__ Wo,
    const float* __restrict__ bq, const float* __restrict__ bk, const float* __restrict__ bv,
    const float* __restrict__ W1, const float* __restrict__ b1,
    const float* __restrict__ W2, const float* __restrict__ b2,
    ushort* __restrict__ xb, ushort* __restrict__ Wqkvt, ushort* __restrict__ Wot,
    float* __restrict__ biasqkv, ushort* __restrict__ bias_g) {
    const int bi = blockIdx.x;
    const int tid = threadIdx.x;
    if (bi < 4096) {
        int i = (bi * 256 + tid) * 4;
        float4 v = *(const float4*)(x + i);
        ushort4 o;
        o.x = f2bf(v.x); o.y = f2bf(v.y); o.z = f2bf(v.z); o.w = f2bf(v.w);
        *(ushort4*)(xb + i) = o;
    } else if (bi < 5120) {
        int f = (bi - 4096) * 256 + tid;  // 0 .. 262143
        if (f < 768 * 256) {
            int n = f >> 8, k = f & 255;
            int seg = n >> 8, nc = n & 255;
            const float* W = (seg == 0) ? Wq : (seg == 1) ? Wk : Wv;
            Wqkvt[f] = f2bf(W[k * 256 + nc]);
        } else {
            int g = f - 768 * 256;
            int n = g >> 8, k = g & 255;
            Wot[g] = f2bf(Wo[k * 256 + n]);
        }
        if (f < 768) biasqkv[f] = (f < 256) ? bq[f] : (f < 512) ? bk[f - 256] : bv[f - 512];
    } else {
        // bias MLP: 8 points per block, 2 per wave
        __shared__ float W1s[96], b1s[32], W2s[256], b2s[8];
        if (tid < 96) W1s[tid] = W1[tid];
        if (tid < 32) b1s[tid] = b1[tid];
        W2s[tid] = W2[tid];
        if (tid < 8) b2s[tid] = b2[tid];
        __syncthreads();
        const int wid = tid >> 6, lane = tid & 63;
        const int s = lane >> 5, j = lane & 31;
        const int p = (bi - 5120) * 8 + wid * 2 + s;
        const int b = p >> 13, n = p & 8191;
        const int nj = idx[(size_t)p * 32 + j];
        const size_t pb = ((size_t)b * NPTS + n) * 3;
        const size_t nb = ((size_t)b * NPTS + nj) * 3;
        const float rx = xyz[pb + 0] - xyz[nb + 0];
        const float ry = xyz[pb + 1] - xyz[nb + 1];
        const float rz = xyz[pb + 2] - xyz[nb + 2];
        float acc[8];
#pragma unroll
        for (int h = 0; h < 8; ++h) acc[h] = b2s[h];
#pragma unroll
        for (int u = 0; u < 32; ++u) {
            float hv = rx * W1s[u] + ry * W1s[32 + u] + rz * W1s[64 + u] + b1s[u];
            hv = fmaxf(hv, 0.f);
#pragma unroll
            for (int h = 0; h < 8; ++h) acc[h] += hv * W2s[u * 8 + h];
        }
#pragma unroll
        for (int h = 0; h < 8; ++h) bias_g[((size_t)p * 8 + h) * 32 + j] = f2bf(acc[h]);
    }
}

// ---------------- QKV GEMM: 128x128 tile, BK=64, XOR-swizzled LDS ----------------
// out[M,768] = A[M,256] @ Wt^T + bias (bf16 out). 32 MFMA per barrier-pair.
__global__ __launch_bounds__(256) void gemm_qkv(const ushort* __restrict__ A,
                                                const ushort* __restrict__ Wt,
                                                const float* __restrict__ bias,
                                                ushort* __restrict__ outp) {
    __shared__ __align__(16) ushort As[128 * 64];  // [m][64], 128-B rows, seg-swizzled
    __shared__ __align__(16) ushort Bs[128 * 64];  // [n][64]
    const int tid = threadIdx.x;
    const int w = tid >> 6, lane = tid & 63;
    const int m0 = blockIdx.y * 128, n0 = blockIdx.x * 128;
    const int wm = (w & 1) * 64, wn = (w >> 1) * 64;
    const int N = 768;

    floatx4 acc[4][4] = {};

    for (int kt = 0; kt < 256; kt += 64) {
        __syncthreads();
        // staging: wave w stages chunks w*4..w*4+3 (each chunk = 8 rows x 128 B = 1 KB)
#pragma unroll
        for (int c4 = 0; c4 < 4; ++c4) {
            const int c = w * 4 + c4;
            const int r = c * 8 + (lane >> 3);
            const int gseg = (lane & 7) ^ (r & 7);  // physical slot (lane&7) holds global seg gseg
            const char* ga = (const char*)(A + (size_t)(m0 + r) * 256 + kt) + gseg * 16;
            const char* gb = (const char*)(Wt + (size_t)(n0 + r) * 256 + kt) + gseg * 16;
            __builtin_amdgcn_global_load_lds((const __attribute__((address_space(1))) void*)ga,
                                             (__attribute__((address_space(3))) void*)((char*)As + c * 1024),
                                             16, 0, 0);
            __builtin_amdgcn_global_load_lds((const __attribute__((address_space(1))) void*)gb,
                                             (__attribute__((address_space(3))) void*)((char*)Bs + c * 1024),
                                             16, 0, 0);
        }
        __syncthreads();

        // fragments: row&7 == lane&7 for all tiles, so phys = s ^ (lane&7)
        bf16x8 af[2][4], bg[2][4];
#pragma unroll
        for (int kk = 0; kk < 2; ++kk) {
            const int s = kk * 4 + (lane >> 4);
            const int phys = s ^ (lane & 7);
#pragma unroll
            for (int i = 0; i < 4; ++i) {
                af[kk][i] = *(const bf16x8*)((const char*)As + (wm + i * 16 + (lane & 15)) * 128 + phys * 16);
                bg[kk][i] = *(const bf16x8*)((const char*)Bs + (wn + i * 16 + (lane & 15)) * 128 + phys * 16);
            }
        }
#pragma unroll
        for (int kk = 0; kk < 2; ++kk)
#pragma unroll
            for (int mi = 0; mi < 4; ++mi)
#pragma unroll
                for (int ni = 0; ni < 4; ++ni)
                    acc[mi][ni] = __builtin_amdgcn_mfma_f32_16x16x32_bf16(af[kk][mi], bg[kk][ni], acc[mi][ni], 0, 0, 0);
    }

#pragma unroll
    for (int ni = 0; ni < 4; ++ni) {
        const int col = n0 + wn + ni * 16 + (lane & 15);
        const float bv = bias[col];
#pragma unroll
        for (int mi = 0; mi < 4; ++mi) {
            const int row0 = m0 + wm + mi * 16 + (lane >> 4) * 4;
#pragma unroll
            for (int r = 0; r < 4; ++r)
                outp[(size_t)(row0 + r) * N + col] = f2bf(acc[mi][ni][r] + bv);
        }
    }
}

// ---------------- O-proj GEMM, 64x64 tile (1024 blocks for occupancy) ----------------
__global__ __launch_bounds__(256) void gemm_mfma64(const ushort* __restrict__ A,
                                                   const ushort* __restrict__ Wt,
                                                   const float* __restrict__ bias,
                                                   float* __restrict__ outv, int N) {
    __shared__ __align__(16) ushort As[64 * 32];
    __shared__ __align__(16) ushort Bs[64 * 32];
    const int tid = threadIdx.x;
    const int w = tid >> 6, lane = tid & 63;
    const int m0 = blockIdx.y * 64, n0 = blockIdx.x * 64;
    const int row = tid >> 2;
    const int col16 = (tid & 3) * 16;

    floatx4 acc[4] = {};

    for (int kt = 0; kt < 256; kt += 32) {
        __syncthreads();
        {
            const char* ga = (const char*)(A + (size_t)(m0 + row) * 256 + kt) + col16;
            const char* gb = (const char*)(Wt + (size_t)(n0 + row) * 256 + kt) + col16;
            __builtin_amdgcn_global_load_lds((const __attribute__((address_space(1))) void*)ga,
                                             (__attribute__((address_space(3))) void*)((char*)As + w * 1024),
                                             16, 0, 0);
            __builtin_amdgcn_global_load_lds((const __attribute__((address_space(1))) void*)gb,
                                             (__attribute__((address_space(3))) void*)((char*)Bs + w * 1024),
                                             16, 0, 0);
        }
        __syncthreads();

        bf16x8 af = *(const bf16x8*)&As[(w * 16 + (lane & 15)) * 32 + (lane >> 4) * 8];
        bf16x8 bg[4];
#pragma unroll
        for (int ni = 0; ni < 4; ++ni)
            bg[ni] = *(const bf16x8*)&Bs[(ni * 16 + (lane & 15)) * 32 + (lane >> 4) * 8];
#pragma unroll
        for (int ni = 0; ni < 4; ++ni)
            acc[ni] = __builtin_amdgcn_mfma_f32_16x16x32_bf16(af, bg[ni], acc[ni], 0, 0, 0);
    }

#pragma unroll
    for (int ni = 0; ni < 4; ++ni) {
        const int col = n0 + ni * 16 + (lane & 15);
        const float bv = bias[col];
        const int row0 = m0 + w * 16 + (lane >> 4) * 4;
#pragma unroll
        for (int r = 0; r < 4; ++r)
            outv[(size_t)(row0 + r) * N + col] = acc[ni][r] + bv;
    }
}

// ---------------- attention: head-sliced, no-max softmax, 16-B gathers ----------------
__global__ __launch_bounds__(256) void attn_kernel(
    const ushort* __restrict__ qkv, const int* __restrict__ idx,
    const ushort* __restrict__ bias_g, ushort* __restrict__ out) {
    __shared__ __align__(16) float q_s[4][2][32];
    __shared__ float e_s[4][2][32];
    __shared__ uint32 off_s[4][2][32];  // neighbor-row byte offsets
    __shared__ float ssum_s[4][2];

    const int tid = threadIdx.x, wid = tid >> 6, lane = tid & 63;
    const int h = blockIdx.x & 7;       // head -> XCD round-robin
    const int pg = blockIdx.x >> 3;
    const int pbase = pg * 8 + wid * 2;
    const char* base = (const char*)qkv;

    const int s = lane >> 5, j = lane & 31;
    const int p = pbase + s;
    const int b = p >> 13;

    // stage: byte offsets of neighbor rows (pitch 1536 B) + q (fp32)
    off_s[wid][s][j] = (uint32)(idx[(size_t)p * 32 + j] + b * NPTS) * 1536u;
    q_s[wid][s][j] = bf1(qkv[(size_t)p * 768 + h * 32 + j]);
    __syncthreads();

    // scores + exp + sum (no max-pass: scores O(1), fp32 exp can't overflow)
    {
        const uint4* kp = (const uint4*)(base + off_s[wid][s][j] + 512 + h * 64);
        float d = 0.f;
#pragma unroll
        for (int c = 0; c < 4; ++c) {
            uint4 kv = kp[c];
            float4 qa = *(const float4*)&q_s[wid][s][c * 8];
            float4 qb = *(const float4*)&q_s[wid][s][c * 8 + 4];
            d += bflo(kv.x) * qa.x + bfhi(kv.x) * qa.y
               + bflo(kv.y) * qa.z + bfhi(kv.y) * qa.w
               + bflo(kv.z) * qb.x + bfhi(kv.z) * qb.y
               + bflo(kv.w) * qb.z + bfhi(kv.w) * qb.w;
        }
        const float sc = d * 0.17677669529663687f + bf1(bias_g[((size_t)p * 8 + h) * 32 + j]);
        const float e = __expf(sc);
        float ssum = e;
#pragma unroll
        for (int msk = 16; msk >= 1; msk >>= 1) ssum += __shfl_xor(ssum, msk, 64);
        e_s[wid][s][j] = e;
        if (j == 0) ssum_s[wid][s] = ssum;
    }
    __syncthreads();

    // PV: lane = (s2 = point, q4 = 16-B dim-quarter, j3 = neighbor subset).
    // Each lane reads uint4 (8 dims) per neighbor -> 4x fewer, 4x wider transactions.
    {
        const int s2 = lane >> 5;
        const int q4 = (lane >> 3) & 3;
        const int j3 = lane & 7;
        const int p2 = pbase + s2;
        float a[8] = {};
#pragma unroll
        for (int t = 0; t < 4; ++t) {
            const int j2 = t * 8 + j3;
            const float wgt = e_s[wid][s2][j2];
            const uint4 v = *(const uint4*)(base + off_s[wid][s2][j2] + 1024 + h * 64 + q4 * 16);
            a[0] += wgt * bflo(v.x); a[1] += wgt * bfhi(v.x);
            a[2] += wgt * bflo(v.y); a[3] += wgt * bfhi(v.y);
            a[4] += wgt * bflo(v.z); a[5] += wgt * bfhi(v.z);
            a[6] += wgt * bflo(v.w); a[7] += wgt * bfhi(v.w);
        }
#pragma unroll
        for (int msk = 1; msk <= 4; msk <<= 1) {
#pragma unroll
            for (int d = 0; d < 8; ++d) a[d] += __shfl_xor(a[d], msk, 64);
        }
        if (j3 == 0) {
            const float rinv = __builtin_amdgcn_rcpf(ssum_s[wid][s2]);
            uint4 ov;
            ov.x = (uint32)f2bf(a[0] * rinv) | ((uint32)f2bf(a[1] * rinv) << 16);
            ov.y = (uint32)f2bf(a[2] * rinv) | ((uint32)f2bf(a[3] * rinv) << 16);
            ov.z = (uint32)f2bf(a[4] * rinv) | ((uint32)f2bf(a[5] * rinv) << 16);
            ov.w = (uint32)f2bf(a[6] * rinv) | ((uint32)f2bf(a[7] * rinv) << 16);
            *(uint4*)(out + (size_t)p2 * 256 + h * 32 + q4 * 8) = ov;
        }
    }
}

// ---------------- launch ----------------
extern "C" void kernel_launch(void* const* d_in, const int* in_sizes, int n_in,
                              void* d_out, int out_size, void* d_ws, size_t ws_size,
                              hipStream_t stream) {
    const float* x   = (const float*)d_in[0];
    const float* xyz = (const float*)d_in[1];
    const int*   idx = (const int*)d_in[2];
    const float* Wq = (const float*)d_in[3];
    const float* bq = (const float*)d_in[4];
    const float* Wk = (const float*)d_in[5];
    const float* bk = (const float*)d_in[6];
    const float* Wv = (const float*)d_in[7];
    const float* bv = (const float*)d_in[8];
    const float* Wo = (const float*)d_in[9];
    const float* bo = (const float*)d_in[10];
    const float* W1 = (const float*)d_in[11];
    const float* b1 = (const float*)d_in[12];
    const float* W2 = (const float*)d_in[13];
    const float* b2 = (const float*)d_in[14];

    char* wsb = (char*)d_ws;
    ushort* x_bf    = (ushort*)wsb;                   // 8 MB (aliased by aout_bf)
    ushort* aout_bf = x_bf;                           // x consumed by gemm_qkv before attn writes
    ushort* qkv_bf  = (ushort*)(wsb + 8388608);       // 25.17 MB
    ushort* Wqkvt   = (ushort*)(wsb + 33554432);      // 384 KB
    ushort* Wot     = (ushort*)(wsb + 33947648);      // 128 KB
    float*  biasqkv = (float*)(wsb + 34078720);       // 3 KB
    ushort* bias_g  = (ushort*)(wsb + 34081792);      // 8 MB

    prep_kernel<<<7168, 256, 0, stream>>>(x, xyz, idx, Wq, Wk, Wv, Wo, bq, bk, bv,
                                          W1, b1, W2, b2, x_bf, Wqkvt, Wot, biasqkv, bias_g);

    gemm_qkv<<<dim3(6, 128), 256, 0, stream>>>(x_bf, Wqkvt, biasqkv, qkv_bf);

    attn_kernel<<<16384, 256, 0, stream>>>(qkv_bf, idx, bias_g, aout_bf);

    gemm_mfma64<<<dim3(4, 256), 256, 0, stream>>>(aout_bf, Wot, bo, (float*)d_out, 256);
}

// Round 7
// 184.382 us; speedup vs baseline: 1.0995x; 1.0763x over previous
//
#include <hip/hip_runtime.h>
#include <hip/hip_bf16.h>

typedef unsigned int uint32;
typedef unsigned short ushort;
typedef __attribute__((ext_vector_type(4))) float floatx4;
typedef __attribute__((ext_vector_type(8))) __bf16 bf16x8;

#define NPTS 8192
#define HSZ 524288  // 16384*32 elements per head slice

// ---------------- bf16 helpers (RNE) ----------------
__device__ __forceinline__ ushort f2bf(float f) {
    uint32 u = __float_as_uint(f);
    uint32 r = (u + 0x7fffu + ((u >> 16) & 1u)) >> 16;
    return (ushort)r;
}
__device__ __forceinline__ float bf1(ushort u) { return __uint_as_float((uint32)u << 16); }
__device__ __forceinline__ float bflo(uint32 u) { return __uint_as_float(u << 16); }
__device__ __forceinline__ float bfhi(uint32 u) { return __uint_as_float(u & 0xffff0000u); }

// ---------------- prep: cast x -> bf16 | pack weights | bias-MLP (head-major) ----------------
__global__ __launch_bounds__(256) void prep_kernel(
    const float* __restrict__ x, const float* __restrict__ xyz, const int* __restrict__ idx,
    const float* __restrict__ Wq, const float* __restrict__ Wk,
    const float* __restrict__ Wv, const float* __restrict__ Wo,
    const float* __restrict__ bq, const float* __restrict__ bk, const float* __restrict__ bv,
    const float* __restrict__ W1, const float* __restrict__ b1,
    const float* __restrict__ W2, const float* __restrict__ b2,
    ushort* __restrict__ xb, ushort* __restrict__ Wqkvt, ushort* __restrict__ Wot,
    float* __restrict__ biasqkv, ushort* __restrict__ bias_hg) {
    const int bi = blockIdx.x;
    const int tid = threadIdx.x;
    if (bi < 4096) {
        int i = (bi * 256 + tid) * 4;
        float4 v = *(const float4*)(x + i);
        ushort4 o;
        o.x = f2bf(v.x); o.y = f2bf(v.y); o.z = f2bf(v.z); o.w = f2bf(v.w);
        *(ushort4*)(xb + i) = o;
    } else if (bi < 5120) {
        int f = (bi - 4096) * 256 + tid;  // 0 .. 262143
        if (f < 768 * 256) {
            int n = f >> 8, k = f & 255;
            int seg = n >> 8, nc = n & 255;
            const float* W = (seg == 0) ? Wq : (seg == 1) ? Wk : Wv;
            Wqkvt[f] = f2bf(W[k * 256 + nc]);
        } else {
            int g = f - 768 * 256;
            int n = g >> 8, k = g & 255;
            Wot[g] = f2bf(Wo[k * 256 + n]);
        }
        if (f < 768) biasqkv[f] = (f < 256) ? bq[f] : (f < 512) ? bk[f - 256] : bv[f - 512];
    } else {
        // bias MLP: 8 points per block, 2 per wave; head-major output [h][p][j]
        __shared__ float W1s[96], b1s[32], W2s[256], b2s[8];
        if (tid < 96) W1s[tid] = W1[tid];
        if (tid < 32) b1s[tid] = b1[tid];
        W2s[tid] = W2[tid];
        if (tid < 8) b2s[tid] = b2[tid];
        __syncthreads();
        const int wid = tid >> 6, lane = tid & 63;
        const int s = lane >> 5, j = lane & 31;
        const int p = (bi - 5120) * 8 + wid * 2 + s;
        const int b = p >> 13, n = p & 8191;
        const int nj = idx[(size_t)p * 32 + j];
        const size_t pb = ((size_t)b * NPTS + n) * 3;
        const size_t nb = ((size_t)b * NPTS + nj) * 3;
        const float rx = xyz[pb + 0] - xyz[nb + 0];
        const float ry = xyz[pb + 1] - xyz[nb + 1];
        const float rz = xyz[pb + 2] - xyz[nb + 2];
        float acc[8];
#pragma unroll
        for (int h = 0; h < 8; ++h) acc[h] = b2s[h];
#pragma unroll
        for (int u = 0; u < 32; ++u) {
            float hv = rx * W1s[u] + ry * W1s[32 + u] + rz * W1s[64 + u] + b1s[u];
            hv = fmaxf(hv, 0.f);
#pragma unroll
            for (int h = 0; h < 8; ++h) acc[h] += hv * W2s[u * 8 + h];
        }
#pragma unroll
        for (int h = 0; h < 8; ++h) bias_hg[(size_t)h * HSZ + p * 32 + j] = f2bf(acc[h]);
    }
}

// ---------------- QKV GEMM: 128x128 tile, BK=64, XOR-swizzled LDS ----------------
// out scattered head-major: qh/kh/vh[h][p][32]
__global__ __launch_bounds__(256) void gemm_qkv(const ushort* __restrict__ A,
                                                const ushort* __restrict__ Wt,
                                                const float* __restrict__ bias,
                                                ushort* __restrict__ qh, ushort* __restrict__ kh,
                                                ushort* __restrict__ vh) {
    __shared__ __align__(16) ushort As[128 * 64];
    __shared__ __align__(16) ushort Bs[128 * 64];
    const int tid = threadIdx.x;
    const int w = tid >> 6, lane = tid & 63;
    const int m0 = blockIdx.y * 128, n0 = blockIdx.x * 128;
    const int wm = (w & 1) * 64, wn = (w >> 1) * 64;

    floatx4 acc[4][4] = {};

    for (int kt = 0; kt < 256; kt += 64) {
        __syncthreads();
#pragma unroll
        for (int c4 = 0; c4 < 4; ++c4) {
            const int c = w * 4 + c4;
            const int r = c * 8 + (lane >> 3);
            const int gseg = (lane & 7) ^ (r & 7);
            const char* ga = (const char*)(A + (size_t)(m0 + r) * 256 + kt) + gseg * 16;
            const char* gb = (const char*)(Wt + (size_t)(n0 + r) * 256 + kt) + gseg * 16;
            __builtin_amdgcn_global_load_lds((const __attribute__((address_space(1))) void*)ga,
                                             (__attribute__((address_space(3))) void*)((char*)As + c * 1024),
                                             16, 0, 0);
            __builtin_amdgcn_global_load_lds((const __attribute__((address_space(1))) void*)gb,
                                             (__attribute__((address_space(3))) void*)((char*)Bs + c * 1024),
                                             16, 0, 0);
        }
        __syncthreads();

        bf16x8 af[2][4], bg[2][4];
#pragma unroll
        for (int kk = 0; kk < 2; ++kk) {
            const int s = kk * 4 + (lane >> 4);
            const int phys = s ^ (lane & 7);
#pragma unroll
            for (int i = 0; i < 4; ++i) {
                af[kk][i] = *(const bf16x8*)((const char*)As + (wm + i * 16 + (lane & 15)) * 128 + phys * 16);
                bg[kk][i] = *(const bf16x8*)((const char*)Bs + (wn + i * 16 + (lane & 15)) * 128 + phys * 16);
            }
        }
#pragma unroll
        for (int kk = 0; kk < 2; ++kk)
#pragma unroll
            for (int mi = 0; mi < 4; ++mi)
#pragma unroll
                for (int ni = 0; ni < 4; ++ni)
                    acc[mi][ni] = __builtin_amdgcn_mfma_f32_16x16x32_bf16(af[kk][mi], bg[kk][ni], acc[mi][ni], 0, 0, 0);
    }

#pragma unroll
    for (int ni = 0; ni < 4; ++ni) {
        const int col = n0 + wn + ni * 16 + (lane & 15);  // 0..767
        const int seg = col >> 8;
        const int head = (col >> 5) & 7;
        const int dim = col & 31;
        ushort* segp = (seg == 0) ? qh : (seg == 1) ? kh : vh;
        const float bv = bias[col];
#pragma unroll
        for (int mi = 0; mi < 4; ++mi) {
            const int row0 = m0 + wm + mi * 16 + (lane >> 4) * 4;
#pragma unroll
            for (int r = 0; r < 4; ++r)
                segp[(size_t)head * HSZ + (size_t)(row0 + r) * 32 + dim] = f2bf(acc[mi][ni][r] + bv);
        }
    }
}

// ---------------- O-proj GEMM, 64x64 tile ----------------
__global__ __launch_bounds__(256) void gemm_mfma64(const ushort* __restrict__ A,
                                                   const ushort* __restrict__ Wt,
                                                   const float* __restrict__ bias,
                                                   float* __restrict__ outv, int N) {
    __shared__ __align__(16) ushort As[64 * 32];
    __shared__ __align__(16) ushort Bs[64 * 32];
    const int tid = threadIdx.x;
    const int w = tid >> 6, lane = tid & 63;
    const int m0 = blockIdx.y * 64, n0 = blockIdx.x * 64;
    const int row = tid >> 2;
    const int col16 = (tid & 3) * 16;

    floatx4 acc[4] = {};

    for (int kt = 0; kt < 256; kt += 32) {
        __syncthreads();
        {
            const char* ga = (const char*)(A + (size_t)(m0 + row) * 256 + kt) + col16;
            const char* gb = (const char*)(Wt + (size_t)(n0 + row) * 256 + kt) + col16;
            __builtin_amdgcn_global_load_lds((const __attribute__((address_space(1))) void*)ga,
                                             (__attribute__((address_space(3))) void*)((char*)As + w * 1024),
                                             16, 0, 0);
            __builtin_amdgcn_global_load_lds((const __attribute__((address_space(1))) void*)gb,
                                             (__attribute__((address_space(3))) void*)((char*)Bs + w * 1024),
                                             16, 0, 0);
        }
        __syncthreads();

        bf16x8 af = *(const bf16x8*)&As[(w * 16 + (lane & 15)) * 32 + (lane >> 4) * 8];
        bf16x8 bg[4];
#pragma unroll
        for (int ni = 0; ni < 4; ++ni)
            bg[ni] = *(const bf16x8*)&Bs[(ni * 16 + (lane & 15)) * 32 + (lane >> 4) * 8];
#pragma unroll
        for (int ni = 0; ni < 4; ++ni)
            acc[ni] = __builtin_amdgcn_mfma_f32_16x16x32_bf16(af, bg[ni], acc[ni], 0, 0, 0);
    }

#pragma unroll
    for (int ni = 0; ni < 4; ++ni) {
        const int col = n0 + ni * 16 + (lane & 15);
        const float bv = bias[col];
        const int row0 = m0 + w * 16 + (lane >> 4) * 4;
#pragma unroll
        for (int r = 0; r < 4; ++r)
            outv[(size_t)(row0 + r) * N + col] = acc[ni][r] + bv;
    }
}

// ---------------- attention: time-phased heads + head-major dense layout ----------------
// blockIdx = head*2048 + pg: resident blocks cluster on 1-2 heads, so every
// XCD's L2 holds the current head's K+V (2 MB) regardless of XCD mapping.
__global__ __launch_bounds__(256) void attn_kernel(
    const ushort* __restrict__ qh, const ushort* __restrict__ kh, const ushort* __restrict__ vh,
    const int* __restrict__ idx, const ushort* __restrict__ bias_hg, ushort* __restrict__ out) {
    __shared__ __align__(16) float q_s[4][2][32];
    __shared__ float e_s[4][2][32];
    __shared__ uint32 off_s[4][2][32];  // neighbor byte offsets within head slice
    __shared__ float ssum_s[4][2];

    const int tid = threadIdx.x, wid = tid >> 6, lane = tid & 63;
    const int h = blockIdx.x >> 11;       // head phase (slow-varying)
    const int pg = blockIdx.x & 2047;
    const int pbase = pg * 8 + wid * 2;

    const char* kh_h = (const char*)(kh + (size_t)h * HSZ);
    const char* vh_h = (const char*)(vh + (size_t)h * HSZ);

    const int s = lane >> 5, j = lane & 31;
    const int p = pbase + s;
    const int b = p >> 13;

    // stage: neighbor byte offsets (64 B per row in head slice) + q (fp32)
    off_s[wid][s][j] = (uint32)(idx[(size_t)p * 32 + j] + b * NPTS) * 64u;
    q_s[wid][s][j] = bf1(qh[(size_t)h * HSZ + p * 32 + j]);
    __syncthreads();

    // scores + exp + sum (no max-pass)
    {
        const uint4* kp = (const uint4*)(kh_h + off_s[wid][s][j]);
        float d = 0.f;
#pragma unroll
        for (int c = 0; c < 4; ++c) {
            uint4 kv = kp[c];
            float4 qa = *(const float4*)&q_s[wid][s][c * 8];
            float4 qb = *(const float4*)&q_s[wid][s][c * 8 + 4];
            d += bflo(kv.x) * qa.x + bfhi(kv.x) * qa.y
               + bflo(kv.y) * qa.z + bfhi(kv.y) * qa.w
               + bflo(kv.z) * qb.x + bfhi(kv.z) * qb.y
               + bflo(kv.w) * qb.z + bfhi(kv.w) * qb.w;
        }
        const float sc = d * 0.17677669529663687f + bf1(bias_hg[(size_t)h * HSZ + p * 32 + j]);
        const float e = __expf(sc);
        float ssum = e;
#pragma unroll
        for (int msk = 16; msk >= 1; msk >>= 1) ssum += __shfl_xor(ssum, msk, 64);
        e_s[wid][s][j] = e;
        if (j == 0) ssum_s[wid][s] = ssum;
    }
    __syncthreads();

    // PV: lane = (s2, hj = neighbor-half, d2 = dim-pair); 16 lanes cover a 64-B V slice
    {
        const int s2 = lane >> 5, hj = (lane >> 4) & 1, d2 = lane & 15;
        const int p2 = pbase + s2;
        const float rinv = __builtin_amdgcn_rcpf(ssum_s[wid][s2]);
        float ax = 0.f, ay = 0.f;
#pragma unroll
        for (int jj = 0; jj < 16; ++jj) {
            const int j2 = hj * 16 + jj;
            const float wgt = e_s[wid][s2][j2];
            const uint32 v = *(const uint32*)(vh_h + off_s[wid][s2][j2] + d2 * 4);
            ax += wgt * bflo(v);
            ay += wgt * bfhi(v);
        }
        ax += __shfl_xor(ax, 16, 64);
        ay += __shfl_xor(ay, 16, 64);
        if (hj == 0) {
            const uint32 o = (uint32)f2bf(ax * rinv) | ((uint32)f2bf(ay * rinv) << 16);
            *(uint32*)(out + (size_t)p2 * 256 + h * 32 + d2 * 2) = o;
        }
    }
}

// ---------------- launch ----------------
extern "C" void kernel_launch(void* const* d_in, const int* in_sizes, int n_in,
                              void* d_out, int out_size, void* d_ws, size_t ws_size,
                              hipStream_t stream) {
    const float* x   = (const float*)d_in[0];
    const float* xyz = (const float*)d_in[1];
    const int*   idx = (const int*)d_in[2];
    const float* Wq = (const float*)d_in[3];
    const float* bq = (const float*)d_in[4];
    const float* Wk = (const float*)d_in[5];
    const float* bk = (const float*)d_in[6];
    const float* Wv = (const float*)d_in[7];
    const float* bv = (const float*)d_in[8];
    const float* Wo = (const float*)d_in[9];
    const float* bo = (const float*)d_in[10];
    const float* W1 = (const float*)d_in[11];
    const float* b1 = (const float*)d_in[12];
    const float* W2 = (const float*)d_in[13];
    const float* b2 = (const float*)d_in[14];

    char* wsb = (char*)d_ws;
    ushort* x_bf    = (ushort*)wsb;                   // 8 MB (aliased by aout_bf)
    ushort* aout_bf = x_bf;                           // x consumed by gemm_qkv before attn writes
    ushort* qh      = (ushort*)(wsb + 8388608);       // 8 MB [8][16384][32]
    ushort* kh      = (ushort*)(wsb + 16777216);      // 8 MB
    ushort* vh      = (ushort*)(wsb + 25165824);      // 8 MB
    ushort* bias_hg = (ushort*)(wsb + 33554432);      // 8 MB [8][16384][32]
    ushort* Wqkvt   = (ushort*)(wsb + 41943040);      // 384 KB
    ushort* Wot     = (ushort*)(wsb + 42336256);      // 128 KB
    float*  biasqkv = (float*)(wsb + 42467328);       // 3 KB

    prep_kernel<<<7168, 256, 0, stream>>>(x, xyz, idx, Wq, Wk, Wv, Wo, bq, bk, bv,
                                          W1, b1, W2, b2, x_bf, Wqkvt, Wot, biasqkv, bias_hg);

    gemm_qkv<<<dim3(6, 128), 256, 0, stream>>>(x_bf, Wqkvt, biasqkv, qh, kh, vh);

    attn_kernel<<<16384, 256, 0, stream>>>(qh, kh, vh, idx, bias_hg, aout_bf);

    gemm_mfma64<<<dim3(4, 256), 256, 0, stream>>>(aout_bf, Wot, bo, (float*)d_out, 256);
}